// Round 4
// baseline (471.124 us; speedup 1.0000x reference)
//
#include <hip/hip_runtime.h>
#include <hip/hip_bf16.h>

#define N 8192
#define D 128
#define BM 128
#define BN 128
#define DSTRIDE 132   // bf16 dist tile stride (+4 pad) -> conflict-free write/read

typedef __bf16 bf16x8 __attribute__((ext_vector_type(8)));
typedef __bf16 bf16x4 __attribute__((ext_vector_type(4)));
typedef __bf16 bf16x2 __attribute__((ext_vector_type(2)));
typedef float f32x4 __attribute__((ext_vector_type(4)));

// Prep: Wb = bf16(W) ; sq[i] = sum_k W[i][k]^2 ; copy W to out+1 ; zero out[0]
__global__ __launch_bounds__(256) void prep_kernel(const float* __restrict__ W,
                                                   float* __restrict__ out,
                                                   float* __restrict__ sq,
                                                   __bf16* __restrict__ Wb) {
    const int wave = threadIdx.x >> 6;
    const int lane = threadIdx.x & 63;
    const int row = blockIdx.x * 4 + wave;
    const size_t base = (size_t)row * D + lane * 2;
    const float2 v = *(const float2*)(&W[base]);
    out[1 + base] = v.x;           // out+1 is only 4B-aligned; scalar stores
    out[2 + base] = v.y;
    bf16x2 b;
    b[0] = (__bf16)v.x;
    b[1] = (__bf16)v.y;
    *(bf16x2*)(&Wb[base]) = b;
    float s = v.x * v.x + v.y * v.y;
    for (int off = 32; off > 0; off >>= 1) s += __shfl_down(s, off, 64);
    if (lane == 0) sq[row] = s;
    if (row == 0 && threadIdx.x == 0) out[0] = 0.0f;
}

// K1: per 128x128 tile, Gram via MFMA -> dist = sqrt(max(sq_i+sq_j-2g,0)) -> bf16
// tile in LDS -> coalesced bf16x8 stores to Dist (row-major, same layout as A).
__global__ __launch_bounds__(256, 4) void dist_kernel(const __bf16* __restrict__ Wb,
                                                      const float* __restrict__ sq,
                                                      __bf16* __restrict__ Dist) {
    __shared__ __align__(16) __bf16 dist_lds[BM * DSTRIDE];

    const int tid = threadIdx.x;
    const int wave = tid >> 6;
    const int lane = tid & 63;
    const int wr = (wave >> 1) * 64;
    const int wc = (wave & 1) * 64;
    const int l15 = lane & 15;
    const int quad = lane >> 4;
    const int i0 = blockIdx.y * BM;
    const int j0 = blockIdx.x * BN;

    // A/B fragment layout for mfma_f32_16x16x32_bf16: [m = lane&15][k = quad*8 + j]
    const __bf16* Af = Wb + (size_t)(i0 + wr + l15) * D + quad * 8;
    const __bf16* Bf = Wb + (size_t)(j0 + wc + l15) * D + quad * 8;

    f32x4 acc[4][4] = {};
#pragma unroll
    for (int kk = 0; kk < D; kk += 32) {
        bf16x8 a[4], b[4];
#pragma unroll
        for (int ti = 0; ti < 4; ++ti)
            a[ti] = *(const bf16x8*)(Af + (size_t)(ti * 16) * D + kk);
#pragma unroll
        for (int tj = 0; tj < 4; ++tj)
            b[tj] = *(const bf16x8*)(Bf + (size_t)(tj * 16) * D + kk);
#pragma unroll
        for (int ti = 0; ti < 4; ++ti)
#pragma unroll
            for (int tj = 0; tj < 4; ++tj)
                acc[ti][tj] = __builtin_amdgcn_mfma_f32_16x16x32_bf16(a[ti], b[tj], acc[ti][tj], 0, 0, 0);
    }

    // C/D mapping (m89-verified): col = lane&15, row = quad*4 + reg
    float sqi[4][4];
#pragma unroll
    for (int ti = 0; ti < 4; ++ti)
#pragma unroll
        for (int r = 0; r < 4; ++r)
            sqi[ti][r] = sq[i0 + wr + ti * 16 + quad * 4 + r];

#pragma unroll
    for (int ti = 0; ti < 4; ++ti) {
#pragma unroll
        for (int tj = 0; tj < 4; ++tj) {
            const int col = wc + tj * 16 + l15;
            const float sqj = sq[j0 + col];
#pragma unroll
            for (int r = 0; r < 4; ++r) {
                const int row = wr + ti * 16 + quad * 4 + r;
                const float d2 = sqi[ti][r] + sqj - 2.0f * acc[ti][tj][r];
                dist_lds[row * DSTRIDE + col] = (__bf16)__builtin_amdgcn_sqrtf(fmaxf(d2, 0.0f));
            }
        }
    }
    __syncthreads();

    // Store tile: thread covers (row = pass*16 + tid>>4, cols (tid&15)*8..+8)
    const int sr = tid >> 4;
    const int sc = (tid & 15) * 8;
#pragma unroll
    for (int pass = 0; pass < 8; ++pass) {
        const int row = pass * 16 + sr;
        const bf16x8 v = *(const bf16x8*)(&dist_lds[row * DSTRIDE + sc]);
        *(bf16x8*)(&Dist[(size_t)(i0 + row) * N + j0 + sc]) = v;
    }
}

// K2: pure stream. A and Dist have identical flat layout; batch-issue all loads
// (8 float4 + 8 bf16x4 in flight per thread) then consume.
__global__ __launch_bounds__(256) void reduce_kernel(const float* __restrict__ A,
                                                     const __bf16* __restrict__ Dist,
                                                     float* __restrict__ out) {
    const int tid = threadIdx.x;
    const size_t gid = (size_t)blockIdx.x * 256 + tid;   // float4-unit index
    const size_t stride = (size_t)8192 * 256;            // 2,097,152 float4 units

    float4 av[8];
    bf16x4 dv[8];
#pragma unroll
    for (int k = 0; k < 8; ++k)
        av[k] = *(const float4*)(&A[4 * (gid + (size_t)k * stride)]);
#pragma unroll
    for (int k = 0; k < 8; ++k)
        dv[k] = *(const bf16x4*)(&Dist[4 * (gid + (size_t)k * stride)]);

    float local = 0.0f;
#pragma unroll
    for (int k = 0; k < 8; ++k)
        local += av[k].x * (float)dv[k][0] + av[k].y * (float)dv[k][1]
               + av[k].z * (float)dv[k][2] + av[k].w * (float)dv[k][3];

    const int lane = tid & 63;
    for (int off = 32; off > 0; off >>= 1) local += __shfl_down(local, off, 64);
    __shared__ float red[4];
    if (lane == 0) red[tid >> 6] = local;
    __syncthreads();
    if (tid == 0) atomicAdd(out, red[0] + red[1] + red[2] + red[3]);
}

extern "C" void kernel_launch(void* const* d_in, const int* in_sizes, int n_in,
                              void* d_out, int out_size, void* d_ws, size_t ws_size,
                              hipStream_t stream) {
    const float* A = (const float*)d_in[0];
    const float* W = (const float*)d_in[1];
    float* out = (float*)d_out;
    float* sq = (float*)d_ws;                                  // 32 KB
    __bf16* Wb = (__bf16*)((char*)d_ws + 32 * 1024);           // 2 MB
    __bf16* Dist = (__bf16*)((char*)d_ws + 4 * 1024 * 1024);   // 128 MB

    prep_kernel<<<N / 4, 256, 0, stream>>>(W, out, sq, Wb);
    dim3 grid(N / BN, N / BM);
    dist_kernel<<<grid, 256, 0, stream>>>(Wb, sq, Dist);
    reduce_kernel<<<8192, 256, 0, stream>>>(A, Dist, out);
}

// Round 5
// 388.367 us; speedup vs baseline: 1.2131x; 1.2131x over previous
//
#include <hip/hip_runtime.h>
#include <hip/hip_bf16.h>

#define N 8192
#define D 128
#define BM 128
#define BN 128
#define DSTRIDE 132   // bf16 dist tile stride (+4 pad); measured 0 bank conflicts in R3

typedef __bf16 bf16x8 __attribute__((ext_vector_type(8)));
typedef __bf16 bf16x4 __attribute__((ext_vector_type(4)));
typedef __bf16 bf16x2 __attribute__((ext_vector_type(2)));
typedef float f32x4 __attribute__((ext_vector_type(4)));

// Prep: Wb = bf16(W) ; sq[i] = sum_k W[i][k]^2 ; copy W to out+1 ; zero out[0]
__global__ __launch_bounds__(256) void prep_kernel(const float* __restrict__ W,
                                                   float* __restrict__ out,
                                                   float* __restrict__ sq,
                                                   __bf16* __restrict__ Wb) {
    const int wave = threadIdx.x >> 6;
    const int lane = threadIdx.x & 63;
    const int row = blockIdx.x * 4 + wave;
    const size_t base = (size_t)row * D + lane * 2;
    const float2 v = *(const float2*)(&W[base]);
    out[1 + base] = v.x;           // out+1 is only 4B-aligned; scalar stores
    out[2 + base] = v.y;
    bf16x2 b;
    b[0] = (__bf16)v.x;
    b[1] = (__bf16)v.y;
    *(bf16x2*)(&Wb[base]) = b;
    float s = v.x * v.x + v.y * v.y;
    for (int off = 32; off > 0; off >>= 1) s += __shfl_down(s, off, 64);
    if (lane == 0) sq[row] = s;
    if (row == 0 && threadIdx.x == 0) out[0] = 0.0f;
}

// Fused: Gram via MFMA (frags direct from L2-resident bf16 Wb), dist -> LDS,
// A-tile batch-prefetched into registers early and consumed after the barrier.
__global__ __launch_bounds__(256, 2) void lap_kernel(const float* __restrict__ A,
                                                     const __bf16* __restrict__ Wb,
                                                     const float* __restrict__ sq,
                                                     float* __restrict__ out) {
    __shared__ __align__(16) __bf16 dist_lds[BM * DSTRIDE];  // 33.8 KB

    const int tid = threadIdx.x;
    const int wave = tid >> 6;
    const int lane = tid & 63;
    const int wr = (wave >> 1) * 64;
    const int wc = (wave & 1) * 64;
    const int l15 = lane & 15;
    const int quad = lane >> 4;
    const int i0 = blockIdx.y * BM;
    const int j0 = blockIdx.x * BN;

    // A/B fragment layout for mfma_f32_16x16x32_bf16: [m = lane&15][k = quad*8 + j]
    const __bf16* Af = Wb + (size_t)(i0 + wr + l15) * D + quad * 8;
    const __bf16* Bf = Wb + (size_t)(j0 + wc + l15) * D + quad * 8;

    // --- issue k-chunk 0 fragment loads (L2/LLC) ---
    bf16x8 a0[4], b0[4], a1[4], b1[4];
#pragma unroll
    for (int t = 0; t < 4; ++t) {
        a0[t] = *(const bf16x8*)(Af + (size_t)(t * 16) * D);
        b0[t] = *(const bf16x8*)(Bf + (size_t)(t * 16) * D);
    }

    // --- batch-issue ALL 16 A-tile loads (HBM); consumed after the barrier ---
    const int r8 = tid >> 5;          // 0..7
    const int c4 = (tid & 31) * 4;    // 0,4,...,124
    float4 av[16];
#pragma unroll
    for (int p = 0; p < 16; ++p)
        av[p] = *(const float4*)(&A[(size_t)(i0 + p * 8 + r8) * N + j0 + c4]);

    // --- Gram: software-pipelined over 4 k-chunks ---
    f32x4 acc[4][4] = {};
#pragma unroll
    for (int kc = 0; kc < 4; ++kc) {
        if (kc < 3) {
            const int kk = (kc + 1) * 32;
#pragma unroll
            for (int t = 0; t < 4; ++t) {
                a1[t] = *(const bf16x8*)(Af + (size_t)(t * 16) * D + kk);
                b1[t] = *(const bf16x8*)(Bf + (size_t)(t * 16) * D + kk);
            }
        }
#pragma unroll
        for (int ti = 0; ti < 4; ++ti)
#pragma unroll
            for (int tj = 0; tj < 4; ++tj)
                acc[ti][tj] = __builtin_amdgcn_mfma_f32_16x16x32_bf16(a0[ti], b0[tj], acc[ti][tj], 0, 0, 0);
#pragma unroll
        for (int t = 0; t < 4; ++t) { a0[t] = a1[t]; b0[t] = b1[t]; }
    }

    // --- dist = sqrt(max(sq_i + sq_j - 2g, 0)) -> bf16 LDS tile ---
    // C/D mapping (m89-verified): col = lane&15, row = quad*4 + reg
    float sqi[4][4];
#pragma unroll
    for (int ti = 0; ti < 4; ++ti)
#pragma unroll
        for (int r = 0; r < 4; ++r)
            sqi[ti][r] = sq[i0 + wr + ti * 16 + quad * 4 + r];

#pragma unroll
    for (int ti = 0; ti < 4; ++ti) {
#pragma unroll
        for (int tj = 0; tj < 4; ++tj) {
            const int col = wc + tj * 16 + l15;
            const float sqj = sq[j0 + col];
#pragma unroll
            for (int r = 0; r < 4; ++r) {
                const int row = wr + ti * 16 + quad * 4 + r;
                const float d2 = sqi[ti][r] + sqj - 2.0f * acc[ti][tj][r];
                dist_lds[row * DSTRIDE + col] = (__bf16)__builtin_amdgcn_sqrtf(fmaxf(d2, 0.0f));
            }
        }
    }
    __syncthreads();   // also drains the A prefetch batch (one stall, 16 loads deep)

    // --- consume: registers (A) x LDS (dist) ---
    float local = 0.0f;
#pragma unroll
    for (int p = 0; p < 16; ++p) {
        const bf16x4 dv = *(const bf16x4*)(&dist_lds[(p * 8 + r8) * DSTRIDE + c4]);
        local += av[p].x * (float)dv[0] + av[p].y * (float)dv[1]
               + av[p].z * (float)dv[2] + av[p].w * (float)dv[3];
    }

    // --- block reduce + one atomic per block ---
    for (int off = 32; off > 0; off >>= 1) local += __shfl_down(local, off, 64);
    __shared__ float red[4];
    if (lane == 0) red[wave] = local;
    __syncthreads();
    if (tid == 0) atomicAdd(out, red[0] + red[1] + red[2] + red[3]);
}

extern "C" void kernel_launch(void* const* d_in, const int* in_sizes, int n_in,
                              void* d_out, int out_size, void* d_ws, size_t ws_size,
                              hipStream_t stream) {
    const float* A = (const float*)d_in[0];
    const float* W = (const float*)d_in[1];
    float* out = (float*)d_out;
    float* sq = (float*)d_ws;                         // 32 KB
    __bf16* Wb = (__bf16*)((char*)d_ws + 32 * 1024);  // 2 MB

    prep_kernel<<<N / 4, 256, 0, stream>>>(W, out, sq, Wb);
    dim3 grid(N / BN, N / BM);
    lap_kernel<<<grid, 256, 0, stream>>>(A, Wb, sq, out);
}

// Round 6
// 379.697 us; speedup vs baseline: 1.2408x; 1.0228x over previous
//
#include <hip/hip_runtime.h>
#include <hip/hip_bf16.h>

#define N 8192
#define D 128
#define TS 64                 // tile size
#define JT_PER_BLK 8          // j-tiles per block (same i-band)
#define GROUP_STRIDE 272      // dwords: 4 rows*64 + 16 pad -> conflict-free consume
#define BUF_DWORDS (16 * GROUP_STRIDE)   // 17408 B per tile buffer

typedef __bf16 bf16x8 __attribute__((ext_vector_type(8)));
typedef __bf16 bf16x2 __attribute__((ext_vector_type(2)));
typedef float f32x4 __attribute__((ext_vector_type(4)));

// async 16B global->LDS DMA. LDS dest = wave-uniform base + lane*16 (m104).
__device__ __forceinline__ void cp16_g2s(const float* gp, float* lp) {
    __builtin_amdgcn_global_load_lds(
        (const __attribute__((address_space(1))) unsigned int*)gp,
        (__attribute__((address_space(3))) unsigned int*)lp,
        16, 0, 0);
}

// Prep: Wb = bf16(W) ; sq[i] = sum_k W[i][k]^2 ; copy W to out+1 ; zero out[0]
__global__ __launch_bounds__(256) void prep_kernel(const float* __restrict__ W,
                                                   float* __restrict__ out,
                                                   float* __restrict__ sq,
                                                   __bf16* __restrict__ Wb) {
    const int wave = threadIdx.x >> 6;
    const int lane = threadIdx.x & 63;
    const int row = blockIdx.x * 4 + wave;
    const size_t base = (size_t)row * D + lane * 2;
    const float2 v = *(const float2*)(&W[base]);
    out[1 + base] = v.x;           // out+1 is only 4B-aligned; scalar stores
    out[2 + base] = v.y;
    bf16x2 b;
    b[0] = (__bf16)v.x;
    b[1] = (__bf16)v.y;
    *(bf16x2*)(&Wb[base]) = b;
    float s = v.x * v.x + v.y * v.y;
    for (int off = 32; off > 0; off >>= 1) s += __shfl_down(s, off, 64);
    if (lane == 0) sq[row] = s;
    if (row == 0 && threadIdx.x == 0) out[0] = 0.0f;
}

__global__ __launch_bounds__(256, 4) void lap_kernel(const float* __restrict__ A,
                                                     const __bf16* __restrict__ Wb,
                                                     const float* __restrict__ sq,
                                                     float* __restrict__ out) {
    __shared__ __align__(16) float ldsA[2][BUF_DWORDS];   // 2 x 17.4 KB
    __shared__ float red[4];

    const int tid = threadIdx.x;
    const int wave = tid >> 6;
    const int lane = tid & 63;
    const int l15 = lane & 15;
    const int quad = lane >> 4;
    const int wi = wave >> 1;          // quadrant row (0/1)
    const int wj = wave & 1;           // quadrant col (0/1)

    const int ib = blockIdx.x >> 4;                 // 0..127 i-band
    const int jb = blockIdx.x & 15;                 // 0..15
    const int i0 = ib * TS;
    const int j0base = jb * (TS * JT_PER_BLK);      // 512-col stripe

    // ---- loop-invariant i-side state ----
    // A-operand frags (mfma 16x16x32 layout: [m=lane&15][k=quad*8+j])
    bf16x8 afrag[2][4];
#pragma unroll
    for (int t = 0; t < 2; ++t)
#pragma unroll
        for (int kc = 0; kc < 4; ++kc)
            afrag[t][kc] = *(const bf16x8*)(Wb + (size_t)(i0 + wi * 32 + t * 16 + l15) * D + kc * 32 + quad * 8);

    float sqi[2][4];
#pragma unroll
    for (int t = 0; t < 2; ++t)
#pragma unroll
        for (int r = 0; r < 4; ++r)
            sqi[t][r] = sq[i0 + wi * 32 + t * 16 + quad * 4 + r];

    // ---- DMA lane mapping: group g = 4 rows; lane -> (row g*4+(lane>>4), 4 floats) ----
    const int drow = lane >> 4;
    const int dcol = (lane & 15) * 4;

    // prologue: DMA tile 0 -> buf 0
    {
        const float* gbase = A + (size_t)i0 * N + j0base;
#pragma unroll
        for (int q = 0; q < 4; ++q) {
            const int g = wave * 4 + q;
            cp16_g2s(gbase + (size_t)(g * 4 + drow) * N + dcol, &ldsA[0][g * GROUP_STRIDE]);
        }
    }

    float local = 0.0f;
    int cur = 0;
#pragma unroll 1
    for (int tt = 0; tt < JT_PER_BLK; ++tt) {
        const int j0 = j0base + tt * TS;
        __syncthreads();   // vmcnt(0) drain publishes buf[cur] for the whole block

        // prefetch next tile into the other buffer (drains at NEXT barrier)
        if (tt + 1 < JT_PER_BLK) {
            const float* gbase = A + (size_t)i0 * N + j0 + TS;
#pragma unroll
            for (int q = 0; q < 4; ++q) {
                const int g = wave * 4 + q;
                cp16_g2s(gbase + (size_t)(g * 4 + drow) * N + dcol, &ldsA[cur ^ 1][g * GROUP_STRIDE]);
            }
        }

        // ---- Gram quadrant (32x32) for this wave: b-frags from L2-resident Wb ----
        bf16x8 bfrag[2][4];
#pragma unroll
        for (int t = 0; t < 2; ++t)
#pragma unroll
            for (int kc = 0; kc < 4; ++kc)
                bfrag[t][kc] = *(const bf16x8*)(Wb + (size_t)(j0 + wj * 32 + t * 16 + l15) * D + kc * 32 + quad * 8);

        f32x4 acc[2][2] = {};
#pragma unroll
        for (int kc = 0; kc < 4; ++kc)
#pragma unroll
            for (int ti = 0; ti < 2; ++ti)
#pragma unroll
                for (int tj = 0; tj < 2; ++tj)
                    acc[ti][tj] = __builtin_amdgcn_mfma_f32_16x16x32_bf16(afrag[ti][kc], bfrag[tj][kc], acc[ti][tj], 0, 0, 0);

        // ---- dist + consume, in C/D order (col=lane&15, row=quad*4+reg) ----
        const float* lA = ldsA[cur];
#pragma unroll
        for (int ti = 0; ti < 2; ++ti) {
            const int g = wi * 8 + ti * 4 + quad;   // row group in LDS tile
#pragma unroll
            for (int tj = 0; tj < 2; ++tj) {
                const int colL = wj * 32 + tj * 16 + l15;
                const float sqj = sq[j0 + colL];
#pragma unroll
                for (int r = 0; r < 4; ++r) {
                    const float d2 = sqi[ti][r] + sqj - 2.0f * acc[ti][tj][r];
                    const float dist = __builtin_amdgcn_sqrtf(fmaxf(d2, 0.0f));
                    local += lA[g * GROUP_STRIDE + r * 64 + colL] * dist;
                }
            }
        }
        cur ^= 1;
    }

    // ---- block reduce + one atomic per block ----
    for (int off = 32; off > 0; off >>= 1) local += __shfl_down(local, off, 64);
    if (lane == 0) red[wave] = local;
    __syncthreads();
    if (tid == 0) atomicAdd(out, red[0] + red[1] + red[2] + red[3]);
}

extern "C" void kernel_launch(void* const* d_in, const int* in_sizes, int n_in,
                              void* d_out, int out_size, void* d_ws, size_t ws_size,
                              hipStream_t stream) {
    const float* A = (const float*)d_in[0];
    const float* W = (const float*)d_in[1];
    float* out = (float*)d_out;
    float* sq = (float*)d_ws;                         // 32 KB
    __bf16* Wb = (__bf16*)((char*)d_ws + 32 * 1024);  // 2 MB

    prep_kernel<<<N / 4, 256, 0, stream>>>(W, out, sq, Wb);
    lap_kernel<<<2048, 256, 0, stream>>>(A, Wb, sq, out);
}

// Round 7
// 355.187 us; speedup vs baseline: 1.3264x; 1.0690x over previous
//
#include <hip/hip_runtime.h>
#include <hip/hip_bf16.h>

#define N 8192
#define D 128
#define BM 128
#define BN 128
#define WSTR 136   // bf16 LDS stride: 272 B/row -> 16B-aligned b128, 2-way banks (free)

typedef __bf16 bf16x8 __attribute__((ext_vector_type(8)));
typedef __bf16 bf16x4 __attribute__((ext_vector_type(4)));
typedef __bf16 bf16x2 __attribute__((ext_vector_type(2)));
typedef float f32x4 __attribute__((ext_vector_type(4)));

// Prep: Wb = bf16(W) ; sq[i] = sum_k W[i][k]^2 ; copy W to out+1 ; zero out[0]
__global__ __launch_bounds__(256) void prep_kernel(const float* __restrict__ W,
                                                   float* __restrict__ out,
                                                   float* __restrict__ sq,
                                                   __bf16* __restrict__ Wb) {
    const int wave = threadIdx.x >> 6;
    const int lane = threadIdx.x & 63;
    const int row = blockIdx.x * 4 + wave;
    const size_t base = (size_t)row * D + lane * 2;
    const float2 v = *(const float2*)(&W[base]);
    out[1 + base] = v.x;           // out+1 is only 4B-aligned; scalar stores
    out[2 + base] = v.y;
    bf16x2 b;
    b[0] = (__bf16)v.x;
    b[1] = (__bf16)v.y;
    *(bf16x2*)(&Wb[base]) = b;
    float s = v.x * v.x + v.y * v.y;
    for (int off = 32; off > 0; off >>= 1) s += __shfl_down(s, off, 64);
    if (lane == 0) sq[row] = s;
    if (row == 0 && threadIdx.x == 0) out[0] = 0.0f;
}

// Fused, one 128x128 tile per block:
//   A tile -> registers (batched, issued first);
//   Wi/Wj bf16 tiles -> LDS (coalesced, padded stride);
//   Gram from LDS frags (ds_read_b128) -> dist overlaid in LDS -> consume vs av[].
__global__ __launch_bounds__(256, 2) void lap_kernel(const float* __restrict__ A,
                                                     const __bf16* __restrict__ Wb,
                                                     const float* __restrict__ sq,
                                                     float* __restrict__ out) {
    __shared__ __align__(16) __bf16 ldsW[2 * BM * WSTR];  // Wi | Wj = 69.6 KB
    __bf16* ldsD = ldsW;                                   // dist overlays Wi after Gram
    __shared__ float red[4];

    const int tid = threadIdx.x;
    const int wave = tid >> 6;
    const int lane = tid & 63;
    const int l15 = lane & 15;
    const int quad = lane >> 4;
    const int wr = (wave >> 1) * 64;
    const int wc = (wave & 1) * 64;
    const int i0 = (blockIdx.x >> 6) * BM;
    const int j0 = (blockIdx.x & 63) * BN;

    // ---- 1) batch-issue ALL 16 A-tile float4 loads (HBM); consumed last ----
    const int r8 = tid >> 5;          // 0..7
    const int c4 = (tid & 31) * 4;    // 0,4,...,124
    float4 av[16];
#pragma unroll
    for (int p = 0; p < 16; ++p)
        av[p] = *(const float4*)(&A[(size_t)(i0 + p * 8 + r8) * N + j0 + c4]);

    // ---- 2) stage Wi/Wj (bf16, L2-resident) into LDS, fully coalesced ----
#pragma unroll
    for (int b = 0; b < 8; ++b) {
        const int bl = b * 256 + tid;       // linear 16B-block id, consecutive lanes
        const int row = bl >> 4;
        const int cb = (bl & 15) * 8;       // bf16 col
        *(bf16x8*)(&ldsW[row * WSTR + cb]) =
            *(const bf16x8*)(&Wb[(size_t)(i0 + row) * D + cb]);
        *(bf16x8*)(&ldsW[BM * WSTR + row * WSTR + cb]) =
            *(const bf16x8*)(&Wb[(size_t)(j0 + row) * D + cb]);
    }
    __syncthreads();

    // ---- 3) Gram from LDS: frag layout [m=lane&15][k=quad*8+j] ----
    f32x4 acc[4][4] = {};
#pragma unroll
    for (int kc = 0; kc < 4; ++kc) {
        bf16x8 a[4], b[4];
#pragma unroll
        for (int t = 0; t < 4; ++t)
            a[t] = *(const bf16x8*)(&ldsW[(wr + t * 16 + l15) * WSTR + kc * 32 + quad * 8]);
#pragma unroll
        for (int t = 0; t < 4; ++t)
            b[t] = *(const bf16x8*)(&ldsW[BM * WSTR + (wc + t * 16 + l15) * WSTR + kc * 32 + quad * 8]);
#pragma unroll
        for (int ti = 0; ti < 4; ++ti)
#pragma unroll
            for (int tj = 0; tj < 4; ++tj)
                acc[ti][tj] = __builtin_amdgcn_mfma_f32_16x16x32_bf16(a[ti], b[tj], acc[ti][tj], 0, 0, 0);
    }
    __syncthreads();   // all waves done reading W; LDS reusable for dist

    // ---- 4) dist = sqrt(max(sq_i+sq_j-2g,0)) -> bf16 LDS (C/D order writes) ----
    // C/D mapping (m89-verified): col = lane&15, row = quad*4 + reg
    float sqi[4][4];
#pragma unroll
    for (int ti = 0; ti < 4; ++ti)
#pragma unroll
        for (int r = 0; r < 4; ++r)
            sqi[ti][r] = sq[i0 + wr + ti * 16 + quad * 4 + r];

#pragma unroll
    for (int ti = 0; ti < 4; ++ti) {
#pragma unroll
        for (int tj = 0; tj < 4; ++tj) {
            const int col = wc + tj * 16 + l15;
            const float sqj = sq[j0 + col];
#pragma unroll
            for (int r = 0; r < 4; ++r) {
                const int row = wr + ti * 16 + quad * 4 + r;
                const float d2 = sqi[ti][r] + sqj - 2.0f * acc[ti][tj][r];
                ldsD[row * WSTR + col] = (__bf16)__builtin_amdgcn_sqrtf(fmaxf(d2, 0.0f));
            }
        }
    }
    __syncthreads();

    // ---- 5) consume: av registers (A) x bf16x4 dist from LDS ----
    float local = 0.0f;
#pragma unroll
    for (int p = 0; p < 16; ++p) {
        const bf16x4 dv = *(const bf16x4*)(&ldsD[(p * 8 + r8) * WSTR + c4]);
        local += av[p].x * (float)dv[0] + av[p].y * (float)dv[1]
               + av[p].z * (float)dv[2] + av[p].w * (float)dv[3];
    }

    // ---- block reduce + one atomic per block ----
    for (int off = 32; off > 0; off >>= 1) local += __shfl_down(local, off, 64);
    if (lane == 0) red[wave] = local;
    __syncthreads();
    if (tid == 0) atomicAdd(out, red[0] + red[1] + red[2] + red[3]);
}

extern "C" void kernel_launch(void* const* d_in, const int* in_sizes, int n_in,
                              void* d_out, int out_size, void* d_ws, size_t ws_size,
                              hipStream_t stream) {
    const float* A = (const float*)d_in[0];
    const float* W = (const float*)d_in[1];
    float* out = (float*)d_out;
    float* sq = (float*)d_ws;                         // 32 KB
    __bf16* Wb = (__bf16*)((char*)d_ws + 32 * 1024);  // 2 MB

    prep_kernel<<<N / 4, 256, 0, stream>>>(W, out, sq, Wb);
    lap_kernel<<<4096, 256, 0, stream>>>(A, Wb, sq, out);
}